// Round 3
// baseline (503.122 us; speedup 1.0000x reference)
//
#include <hip/hip_runtime.h>

typedef short  short8  __attribute__((ext_vector_type(8)));
typedef short  short4v __attribute__((ext_vector_type(4)));
typedef float  float4v __attribute__((ext_vector_type(4)));
typedef int    int4v   __attribute__((ext_vector_type(4)));

#define LOG2E 1.4426950408889634f

static __device__ __forceinline__ short f2bf(float f) {
  unsigned u = __builtin_bit_cast(unsigned, f);
  u = (u + 0x7fffu + ((u >> 16) & 1u)) >> 16;   // RNE
  return (short)u;
}
static __device__ __forceinline__ float bf2f(short s) {
  return __builtin_bit_cast(float, ((unsigned)(unsigned short)s) << 16);
}

// ---------------------------------------------------------------------------
// Kernel 1: h = x @ w.T  (8192x256, K=256), hi/lo bf16-split MFMA for ~f32
// accuracy. Writes hT bf16 [256][8192] (ws) and hT f32 [256][8192] (d_out,
// transient scratch — k_gat overwrites d_out later).
// ---------------------------------------------------------------------------
__global__ __launch_bounds__(256) void k_hgemm(
    const float* __restrict__ x, const float* __restrict__ w,
    short* __restrict__ hT, float* __restrict__ hTf) {
  const int I0   = blockIdx.x * 64;
  const int lane = threadIdx.x & 63;
  const int wn   = threadIdx.x >> 6;       // 4 waves split N (cols)
  const int lrow = lane & 15;
  const int lk8  = (lane >> 4) << 3;

  float4v zero4 = {0.f, 0.f, 0.f, 0.f};
  float4v acc[4][4];
  #pragma unroll
  for (int mi = 0; mi < 4; ++mi)
    #pragma unroll
    for (int ni = 0; ni < 4; ++ni) acc[mi][ni] = zero4;

  for (int k0 = 0; k0 < 256; k0 += 32) {
    short8 ah[4], al[4], bh[4], bl[4];
    #pragma unroll
    for (int mi = 0; mi < 4; ++mi) {
      const float* xp = x + (size_t)(I0 + mi * 16 + lrow) * 256 + k0 + lk8;
      float4v va = *(const float4v*)xp;
      float4v vb = *(const float4v*)(xp + 4);
      #pragma unroll
      for (int e = 0; e < 4; ++e) {
        short h = f2bf(va[e]); ah[mi][e] = h;     al[mi][e]     = f2bf(va[e] - bf2f(h));
        h = f2bf(vb[e]);       ah[mi][4 + e] = h; al[mi][4 + e] = f2bf(vb[e] - bf2f(h));
      }
    }
    #pragma unroll
    for (int ni = 0; ni < 4; ++ni) {
      const float* wp = w + (size_t)(wn * 64 + ni * 16 + lrow) * 256 + k0 + lk8;
      float4v va = *(const float4v*)wp;
      float4v vb = *(const float4v*)(wp + 4);
      #pragma unroll
      for (int e = 0; e < 4; ++e) {
        short h = f2bf(va[e]); bh[ni][e] = h;     bl[ni][e]     = f2bf(va[e] - bf2f(h));
        h = f2bf(vb[e]);       bh[ni][4 + e] = h; bl[ni][4 + e] = f2bf(vb[e] - bf2f(h));
      }
    }
    #pragma unroll
    for (int mi = 0; mi < 4; ++mi)
      #pragma unroll
      for (int ni = 0; ni < 4; ++ni) {
        acc[mi][ni] = __builtin_amdgcn_mfma_f32_16x16x32_bf16(al[mi], bh[ni], acc[mi][ni], 0, 0, 0);
        acc[mi][ni] = __builtin_amdgcn_mfma_f32_16x16x32_bf16(ah[mi], bl[ni], acc[mi][ni], 0, 0, 0);
        acc[mi][ni] = __builtin_amdgcn_mfma_f32_16x16x32_bf16(ah[mi], bh[ni], acc[mi][ni], 0, 0, 0);
      }
  }
  const int r0 = (lane >> 4) << 2;   // C/D: col=lane&15, row=(lane>>4)*4+reg
  #pragma unroll
  for (int mi = 0; mi < 4; ++mi)
    #pragma unroll
    for (int ni = 0; ni < 4; ++ni) {
      const int c   = wn * 64 + ni * 16 + lrow;
      const int row = I0 + mi * 16 + r0;
      float4v v = acc[mi][ni];
      short4v sv;
      #pragma unroll
      for (int r = 0; r < 4; ++r) sv[r] = f2bf(v[r]);
      *(short4v*)(hT + (size_t)c * 8192 + row) = sv;
      *(float4v*)(hTf + (size_t)c * 8192 + row) = v;
    }
}

// ---------------------------------------------------------------------------
// Kernel 2: s1 = h@a1, s2 = h@a2 partials (split-K = 2)
// ---------------------------------------------------------------------------
__global__ __launch_bounds__(256) void k_scores1(
    const float* __restrict__ hTf, const float* __restrict__ a,
    float* __restrict__ t1p, float* __restrict__ t2p) {
  const int i = blockIdx.x * 256 + threadIdx.x;
  const int q = blockIdx.y;
  float s1 = 0.f, s2 = 0.f;
  #pragma unroll 8
  for (int kf = q * 128; kf < q * 128 + 128; ++kf) {
    float hv = hTf[(size_t)kf * 8192 + i];
    s1 = fmaf(hv, a[kf], s1);
    s2 = fmaf(hv, a[256 + kf], s2);
  }
  t1p[q * 8192 + i] = s1;
  t2p[q * 8192 + i] = s2;
}

// ---------------------------------------------------------------------------
// Kernel 3: reduce partials, emit exp2 tables:
//   e1f1[i] = {exp2(t1c), exp2(0.2 t1c)},  ef2[j] = {exp2(t2c), exp2(0.2 t2c)}
// so W = adj ? max(e1*e2, f1*f2) : 1   (exp2(max(sc,0.2sc)) separable via
// monotonicity of exp2 — no per-element transcendental in k_gat).
// ---------------------------------------------------------------------------
__global__ __launch_bounds__(256) void k_scores2(
    const float* __restrict__ t1p, const float* __restrict__ t2p,
    float2* __restrict__ e1f1, float2* __restrict__ ef2) {
  const int i = blockIdx.x * 256 + threadIdx.x;
  const float t1 = LOG2E * (t1p[i] + t1p[8192 + i]);
  const float t2 = LOG2E * (t2p[i] + t2p[8192 + i]);
  e1f1[i] = make_float2(exp2f(t1), exp2f(0.2f * t1));
  ef2[i]  = make_float2(exp2f(t2), exp2f(0.2f * t2));
}

// ---------------------------------------------------------------------------
// Kernel 4: fused GAT body — barrier-free, zero LDS.
// Grid 256 x 512 threads; 8 waves = 2 row-groups x 4 col-groups; each wave:
// 16 rows x 64 cols, full K=8192 in 256 steps of 32 j.
// Per step: A-frag (W tile) computed in regs from per-lane adj loads + ef2
// table; 4 MFMAs vs per-lane hT B-frags + 1 Z-MFMA vs B=ones (Z lands in the
// exact C-layout rows for the epilogue divide). adj prefetched 4 steps ahead
// (8-slot reg ring, ~900cy HBM latency), B/ef 1 step ahead (L2-hot).
// ---------------------------------------------------------------------------
__global__ __launch_bounds__(512) void k_gat(
    const int* __restrict__ adj, const short* __restrict__ hT,
    const float2* __restrict__ e1f1, const float* __restrict__ ef2,
    float* __restrict__ out) {
  const int tid = threadIdx.x, lane = tid & 63, wave = tid >> 6;
  const int wm = wave >> 2, wn = wave & 3;
  const int lrow = lane & 15, lk8 = (lane >> 4) << 3;
  const int I0 = blockIdx.x * 32;
  const int row = I0 + wm * 16 + lrow;

  const int* arow = adj + (size_t)row * 8192 + lk8;
  const float4v* ef4 = (const float4v*)ef2;   // chunk idx = j/2 (+c)
  const int efbase = lk8 >> 1;
  const short* bb[4];
  #pragma unroll
  for (int ni = 0; ni < 4; ++ni)
    bb[ni] = hT + (size_t)(wn * 64 + ni * 16 + lrow) * 8192 + lk8;

  const float2 e1f1v = e1f1[row];
  const float e1 = e1f1v.x, f1 = e1f1v.y;

  short8 bone;
  #pragma unroll
  for (int e = 0; e < 8; ++e) bone[e] = (short)0x3F80;   // bf16 1.0

  float4v zero4 = {0.f, 0.f, 0.f, 0.f};
  float4v acc[4] = {zero4, zero4, zero4, zero4};
  float4v accz = zero4;

  int4v   adjr[16];       // 8 step-slots x 2
  float4v efr[2][4];
  short8  br[2][4];

  // prologue: adj steps 0..3, ef/B step 0
  #pragma unroll
  for (int p = 0; p < 4; ++p) {
    adjr[p * 2]     = *(const int4v*)(arow + p * 32);
    adjr[p * 2 + 1] = *(const int4v*)(arow + p * 32 + 4);
  }
  #pragma unroll
  for (int c = 0; c < 4; ++c) efr[0][c] = ef4[efbase + c];
  #pragma unroll
  for (int ni = 0; ni < 4; ++ni) br[0][ni] = *(const short8*)bb[ni];

  for (int g = 0; g < 32; ++g) {
    #pragma unroll
    for (int u = 0; u < 8; ++u) {
      const int s = g * 8 + u;
      const int cb = u & 1, nb = (u + 1) & 1;
      // adj prefetch for step s+4 (slot (u+4)&7) — wraps harmlessly at end
      {
        const int jp = ((s + 4) * 32) & 8191;
        adjr[((u + 4) & 7) * 2]     = *(const int4v*)(arow + jp);
        adjr[((u + 4) & 7) * 2 + 1] = *(const int4v*)(arow + jp + 4);
      }
      // B + ef prefetch for step s+1
      {
        const int jn = ((s + 1) * 32) & 8191;
        #pragma unroll
        for (int ni = 0; ni < 4; ++ni)
          br[nb][ni] = *(const short8*)(bb[ni] + jn);
        const int ei = (jn >> 1) + efbase;
        #pragma unroll
        for (int c = 0; c < 4; ++c) efr[nb][c] = ef4[ei + c];
      }
      // build A-frag: W[row][j0+lk8+e], e=0..7
      const int4v a0 = adjr[u * 2], a1 = adjr[u * 2 + 1];
      int4v pwi;
      #pragma unroll
      for (int k = 0; k < 4; ++k) {
        const float4v ef = efr[cb][k];
        const int adjA = (k < 2) ? a0[2 * k]     : a1[2 * k - 4];
        const int adjB = (k < 2) ? a0[2 * k + 1] : a1[2 * k - 3];
        float wA = adjA ? fmaxf(e1 * ef[0], f1 * ef[1]) : 1.0f;
        float wB = adjB ? fmaxf(e1 * ef[2], f1 * ef[3]) : 1.0f;
        asm("v_cvt_pk_bf16_f32 %0, %1, %2" : "=v"(pwi[k]) : "v"(wA), "v"(wB));
      }
      const short8 af = __builtin_bit_cast(short8, pwi);
      accz = __builtin_amdgcn_mfma_f32_16x16x32_bf16(af, bone, accz, 0, 0, 0);
      #pragma unroll
      for (int ni = 0; ni < 4; ++ni)
        acc[ni] = __builtin_amdgcn_mfma_f32_16x16x32_bf16(af, br[cb][ni], acc[ni], 0, 0, 0);
    }
  }

  // epilogue: out = elu(N/Z); accz[r] is Z for C/D row (lane>>4)*4+r
  float rz[4];
  #pragma unroll
  for (int r = 0; r < 4; ++r) rz[r] = 1.0f / accz[r];
  const int orow0 = I0 + wm * 16 + ((lane >> 4) << 2);
  #pragma unroll
  for (int ni = 0; ni < 4; ++ni) {
    const int col = wn * 64 + ni * 16 + lrow;
    #pragma unroll
    for (int r = 0; r < 4; ++r) {
      float v = acc[ni][r] * rz[r];
      out[(size_t)(orow0 + r) * 256 + col] = (v > 0.f) ? v : expm1f(v);
    }
  }
}

// ---------------------------------------------------------------------------
extern "C" void kernel_launch(void* const* d_in, const int* in_sizes, int n_in,
                              void* d_out, int out_size, void* d_ws, size_t ws_size,
                              hipStream_t stream) {
  const int*   adj = (const int*)d_in[0];
  const float* x   = (const float*)d_in[1];
  const float* w   = (const float*)d_in[2];
  const float* a   = (const float*)d_in[3];
  float* out = (float*)d_out;

  // ws usage: 4 MiB + 256 KiB (within the 4.5 MiB proven-safe bound).
  // hTf (8 MiB f32) lives in d_out transiently; k_gat overwrites d_out.
  char* ws = (char*)d_ws;
  short*  hT   = (short*)(ws + 0);          // 4 MiB  bf16 h^T [256][8192]
  float*  t1p  = (float*)(ws + 4194304);    // 64 KiB (2 x 8192)
  float*  t2p  = (float*)(ws + 4259840);    // 64 KiB
  float2* e1f1 = (float2*)(ws + 4325376);   // 64 KiB
  float2* ef2  = (float2*)(ws + 4390912);   // 64 KiB
  float*  hTf  = (float*)d_out;             // 8 MiB  f32 h^T (transient)

  k_hgemm  <<<128, 256, 0, stream>>>(x, w, hT, hTf);
  k_scores1<<<dim3(32, 2), 256, 0, stream>>>(hTf, a, t1p, t2p);
  k_scores2<<<32, 256, 0, stream>>>(t1p, t2p, e1f1, ef2);
  k_gat    <<<256, 512, 0, stream>>>(adj, hT, e1f1, (const float*)ef2, out);
}